// Round 1
// baseline (3957.624 us; speedup 1.0000x reference)
//
#include <hip/hip_runtime.h>
#include <math.h>

#define BB 16
#define TT 16
#define HH 64
#define WW 64
#define FF 64    // feature channels
#define FG 256   // 4*F (gates i,f,c,o)

#define TY 8
#define TX 8

// Fuse W = kernels + rec_kernels and transpose to layout [t][tap][cin][f][g]
// so a compute thread (owning channel f) loads its 4 gate weights as one float4.
__global__ void fuse_weights(const float* __restrict__ k,
                             const float* __restrict__ rk,
                             float* __restrict__ wf) {
    int idx = blockIdx.x * blockDim.x + threadIdx.x;
    const int total = TT * 9 * FF * FG;   // 2,359,296
    if (idx >= total) return;
    int g    = idx & 3;
    int f    = (idx >> 2) & 63;
    int cin  = (idx >> 8) & 63;
    int rest = idx >> 14;          // t*9 + tap
    int tap  = rest % 9;
    int t    = rest / 9;
    int cout = g * 64 + f;
    size_t src = (((size_t)t * 9 + tap) * FF + cin) * FG + cout;
    wf[idx] = k[src] + rk[src];
}

__device__ __forceinline__ float hsig(float x) {
    return fminf(fmaxf(0.2f * x + 0.5f, 0.0f), 1.0f);
}

// One ConvLSTM step: z = conv3x3_same(h_prev, Wfused) + bias; gates; write c,h.
// Block: 256 threads = 4 wave64. Each block computes an 8x8 spatial tile,
// all 256 output channels. Thread (f = tid&63, pg = tid>>6) computes 16
// positions (2 rows) x 4 gates of channel f.
__global__ void __launch_bounds__(256)
convlstm_step(const float* __restrict__ hbase, size_t h_bstride,
              const float* __restrict__ cin_base,
              float* __restrict__ cout_base,
              float* __restrict__ hout_base, size_t hout_bstride,
              const float* __restrict__ wf,     // [9][64][64][4] for this t
              const float* __restrict__ bias)   // [256] for this t
{
    __shared__ float lds[(TY + 2) * (TX + 2) * FF];   // 10*10*64*4 = 25.6 KB

    const int b   = blockIdx.z;
    const int ty0 = blockIdx.y * TY;
    const int tx0 = blockIdx.x * TX;
    const int tid = threadIdx.x;

    const float* hb = hbase + (size_t)b * h_bstride;

    // Stage h tile with halo (SAME padding -> zeros). Coalesced: lane = channel.
    for (int i = tid; i < 100 * FF; i += 256) {
        int c  = i & 63;
        int p  = i >> 6;
        int py = p / 10, px = p % 10;
        int gy = ty0 + py - 1, gx = tx0 + px - 1;
        float v = 0.0f;
        if (gy >= 0 && gy < HH && gx >= 0 && gx < WW)
            v = hb[((size_t)gy * WW + gx) * FF + c];
        lds[i] = v;
    }
    __syncthreads();

    const int f  = tid & 63;
    const int pg = tid >> 6;   // 0..3
    const int r0 = pg * 2;     // first tile row owned by this thread

    float acc[16][4];
#pragma unroll
    for (int p = 0; p < 16; ++p)
#pragma unroll
        for (int g = 0; g < 4; ++g) acc[p][g] = 0.0f;

    for (int cin = 0; cin < FF; ++cin) {
        // Register-cache the 4x10 halo-row window this thread needs for cin.
        float hreg[4][10];
#pragma unroll
        for (int yy = 0; yy < 4; ++yy)
#pragma unroll
            for (int xx = 0; xx < 10; ++xx)
                hreg[yy][xx] = lds[((r0 + yy) * 10 + xx) * FF + cin];

#pragma unroll
        for (int ky = 0; ky < 3; ++ky)
#pragma unroll
        for (int kx = 0; kx < 3; ++kx) {
            const float4 wv =
                *(const float4*)&wf[(((ky * 3 + kx) * FF + cin) * FF + f) * 4];
#pragma unroll
            for (int p = 0; p < 16; ++p) {
                const int py = p >> 3, px = p & 7;
                const float hv = hreg[py + ky][px + kx];
                acc[p][0] += hv * wv.x;
                acc[p][1] += hv * wv.y;
                acc[p][2] += hv * wv.z;
                acc[p][3] += hv * wv.w;
            }
        }
    }

    const float b0 = bias[f], b1 = bias[64 + f], b2 = bias[128 + f], b3 = bias[192 + f];

#pragma unroll
    for (int p = 0; p < 16; ++p) {
        const int py = r0 + (p >> 3), px = p & 7;
        const int gy = ty0 + py, gx = tx0 + px;
        const size_t off = (((size_t)b * HH + gy) * WW + gx) * FF + f;

        const float zi = acc[p][0] + b0;
        const float zf = acc[p][1] + b1;
        const float zc = acc[p][2] + b2;
        const float zo = acc[p][3] + b3;

        const float ig = hsig(zi);
        const float fg = hsig(zf);
        const float og = hsig(zo);

        const float cprev = cin_base[off];
        const float cn = fg * cprev + ig * tanhf(zc);
        cout_base[off] = cn;
        hout_base[(size_t)b * hout_bstride + ((size_t)gy * WW + gx) * FF + f] =
            og * tanhf(cn);
    }
}

extern "C" void kernel_launch(void* const* d_in, const int* in_sizes, int n_in,
                              void* d_out, int out_size, void* d_ws, size_t ws_size,
                              hipStream_t stream) {
    // setup_inputs order: inputs, h0, c0, kernels, rec_kernels, bias
    const float* h0    = (const float*)d_in[1];
    const float* c0    = (const float*)d_in[2];
    const float* kern  = (const float*)d_in[3];
    const float* rkern = (const float*)d_in[4];
    const float* bias  = (const float*)d_in[5];
    float* out = (float*)d_out;

    float* wf   = (float*)d_ws;                       // 16*9*64*256 floats = 9.4 MB
    float* cbuf = wf + (size_t)TT * 9 * FF * FG;      // 16*64*64*64 floats = 16.8 MB

    const int wtotal = TT * 9 * FF * FG;
    fuse_weights<<<(wtotal + 255) / 256, 256, 0, stream>>>(kern, rkern, wf);

    const size_t HWF  = (size_t)HH * WW * FF;
    dim3 grid(WW / TX, HH / TY, BB);

    for (int t = 0; t < TT; ++t) {
        const float* hb;
        size_t hbs;
        if (t == 0) { hb = h0;                       hbs = HWF; }
        else        { hb = out + (size_t)(t - 1) * HWF; hbs = (size_t)TT * HWF; }
        const float* cb = (t == 0) ? c0 : cbuf;

        convlstm_step<<<grid, 256, 0, stream>>>(
            hb, hbs, cb, cbuf,
            out + (size_t)t * HWF, (size_t)TT * HWF,
            wf + (size_t)t * 9 * FF * FF * 4,
            bias + t * FG);
    }
}

// Round 2
// 1500.196 us; speedup vs baseline: 2.6381x; 2.6381x over previous
//
#include <hip/hip_runtime.h>
#include <math.h>

typedef _Float16 f16;
typedef _Float16 f16x8 __attribute__((ext_vector_type(8)));
typedef float f32x4 __attribute__((ext_vector_type(4)));

#define NB 16      // batch
#define NT 16      // time steps
#define NH 64
#define NW 64
#define NF 64      // features
#define NG 256     // 4*F
#define HWF ((size_t)NH * NW * NF)          // 262144
#define OUT_BSTRIDE ((size_t)NT * HWF)      // d_out batch stride

#define MFMA(a, b, c) __builtin_amdgcn_mfma_f32_16x16x32_f16((a), (b), (c), 0, 0, 0)

__device__ __forceinline__ void gload_lds16(const void* g, void* l) {
    __builtin_amdgcn_global_load_lds(
        (const __attribute__((address_space(1))) unsigned int*)(g),
        (__attribute__((address_space(3))) unsigned int*)(l), 16, 0, 0);
}

__device__ __forceinline__ float hsig(float x) {
    return fminf(fmaxf(0.2f * x + 0.5f, 0.0f), 1.0f);
}

// ---- prologue 1: fuse W+U, split to fp16 hi/lo, transpose to [t*9+tap][cout][hi(64)|lo(64)]
__global__ void fuse_split_w(const float* __restrict__ k, const float* __restrict__ rk,
                             f16* __restrict__ wf2) {
    int idx = blockIdx.x * 256 + threadIdx.x;      // over 16*9*256*64
    if (idx >= NT * 9 * NG * NF) return;
    int cin  = idx & 63;
    int cout = (idx >> 6) & 255;
    int tt   = idx >> 14;                          // t*9 + tap
    size_t src = ((size_t)tt * NF + cin) * NG + cout;
    float w = k[src] + rk[src];
    f16 hi = (f16)w;
    size_t dst = ((size_t)tt * NG + cout) * 128 + cin;
    wf2[dst]      = hi;
    wf2[dst + 64] = (f16)(w - (float)hi);
}

// ---- prologue 2: split h0 to fp16 hi/lo, layout [b][y][x][hi(64)|lo(64)]
__global__ void split_h(const float* __restrict__ h0, f16* __restrict__ h2) {
    int idx = blockIdx.x * 256 + threadIdx.x;      // over 16*64*64*64
    if (idx >= (int)(NB * HWF)) return;
    int f = idx & 63;
    size_t p = (size_t)(idx >> 6);
    float v = h0[idx];
    f16 hi = (f16)v;
    h2[p * 128 + f]      = hi;
    h2[p * 128 + 64 + f] = (f16)(v - (float)hi);
}

// ---- one ConvLSTM step via split-fp16 MFMA implicit conv
// block: 512 threads = 8 waves (2 m-waves x 4 n-waves). Block tile: 128 positions
// (2 image rows) x 256 couts. LDS: h tile [4 rows][64 x][256B hi/lo], XOR-swizzled.
__global__ void __launch_bounds__(512, 2)
convlstm_mfma_step(const f16* __restrict__ h2in,
                   f16* __restrict__ h2out,
                   const float* __restrict__ cprev,
                   float* __restrict__ cnew,
                   float* __restrict__ hout,        // d_out + t*HWF (batch stride OUT_BSTRIDE)
                   const f16* __restrict__ wt,      // [9][256][128] for this t
                   const float* __restrict__ bias)  // [256] for this t
{
    __shared__ __align__(16) unsigned char lds[65536];

    const int tid  = threadIdx.x;
    const int w    = tid >> 6;
    const int lane = tid & 63;
    const int bb   = blockIdx.y;
    const int y0   = blockIdx.x * 2;

    // ---------- stage h tile (rows y0-1 .. y0+2), source-swizzled for conflict-free reads
    {
        const int r  = w >> 1;                 // tile row 0..3
        const int gy = y0 - 1 + r;
        const int xh = (w & 1) * 32;           // half-row start x
        const unsigned ldsbase = r * 16384 + (w & 1) * 8192;
        if (gy >= 0 && gy < NH) {
            const unsigned char* gsrc = (const unsigned char*)h2in +
                ((((size_t)bb * NH + gy) * NW + xh) << 8);     // *256 B per (y,x)
#pragma unroll
            for (int i = 0; i < 8; ++i) {
                unsigned D    = i * 1024 + lane * 16;
                unsigned xrel = i * 4 + (lane >> 4);
                unsigned src  = D ^ ((xrel & 7) << 4);         // pre-swizzled source
                gload_lds16(gsrc + src, (void*)&lds[ldsbase + i * 1024]);
            }
        } else {
            const f16x8 zf = (f16x8)(_Float16)0.0f;
#pragma unroll
            for (int i = 0; i < 8; ++i)
                *(f16x8*)&lds[ldsbase + i * 1024 + lane * 16] = zf;
        }
    }
    __syncthreads();

    // ---------- K loop: 9 taps x 2 cin-halves, 3-term split MFMA
    const int wm = w >> 2;     // 0..1 : which image row pair-half (M)
    const int wn = w & 3;      // 0..3 : gate (N block of 64)
    const int lm = lane & 15;
    const int lg = lane >> 4;

    f32x4 acc[4][4];
#pragma unroll
    for (int mf = 0; mf < 4; ++mf)
#pragma unroll
        for (int nf = 0; nf < 4; ++nf) acc[mf][nf] = (f32x4)0.0f;

    // B base in f16x8 units: (tap*256 + wn*64 + nf*16 + lm)*16 + kk*4 + lg
    const f16x8* wbn = (const f16x8*)wt + ((size_t)(wn * 64 + lm) * 16 + lg);

    f16x8 bh0[4], bl0[4], bh1[4], bl1[4];

    auto loadB0 = [&](int it) {
        int tap = it >> 1, kk = it & 1;
#pragma unroll
        for (int nf = 0; nf < 4; ++nf) {
            const f16x8* p = wbn + (tap * 4096 + nf * 256 + kk * 4);
            bh0[nf] = p[0];
            bl0[nf] = p[8];
        }
    };
    auto loadB1 = [&](int it) {
        int tap = it >> 1, kk = it & 1;
#pragma unroll
        for (int nf = 0; nf < 4; ++nf) {
            const f16x8* p = wbn + (tap * 4096 + nf * 256 + kk * 4);
            bh1[nf] = p[0];
            bl1[nf] = p[8];
        }
    };

    const f16x8 zf16 = (f16x8)(_Float16)0.0f;

#define COMPUTE(IT, BH, BL)                                                     \
    {                                                                           \
        int tap = (IT) >> 1, kk = (IT) & 1;                                     \
        int dy = (tap * 11) >> 5;  /* tap/3 */                                  \
        int dx = tap - dy * 3;                                                  \
        f16x8 Ah[4], Al[4];                                                     \
        _Pragma("unroll")                                                       \
        for (int mf = 0; mf < 4; ++mf) {                                        \
            int tx = mf * 16 + lm + dx - 1;                                     \
            bool bad = (tx < 0) | (tx > 63);                                    \
            int txc = tx < 0 ? 0 : (tx > 63 ? 63 : tx);                         \
            unsigned base = (unsigned)((wm + dy) * 16384 + txc * 256 +          \
                            ((kk * 64 + lg * 16) ^ ((txc & 7) << 4)));          \
            f16x8 ah = *(const f16x8*)&lds[base];                               \
            f16x8 al = *(const f16x8*)&lds[base + 128];                         \
            if (bad) { ah = zf16; al = zf16; }                                  \
            Ah[mf] = ah; Al[mf] = al;                                           \
        }                                                                       \
        _Pragma("unroll")                                                       \
        for (int mf = 0; mf < 4; ++mf)                                          \
        _Pragma("unroll")                                                       \
        for (int nf = 0; nf < 4; ++nf) {                                        \
            acc[mf][nf] = MFMA(Ah[mf], BH[nf], acc[mf][nf]);                    \
            acc[mf][nf] = MFMA(Al[mf], BH[nf], acc[mf][nf]);                    \
            acc[mf][nf] = MFMA(Ah[mf], BL[nf], acc[mf][nf]);                    \
        }                                                                       \
    }

    loadB0(0);
#pragma unroll 1
    for (int it = 0; it < 18; it += 2) {
        loadB1(it + 1);
        COMPUTE(it, bh0, bl0);
        if (it + 2 < 18) loadB0(it + 2);
        COMPUTE(it + 1, bh1, bl1);
    }
#undef COMPUTE

    __syncthreads();

    // ---------- epilogue: exchange z through LDS (gates live in different waves),
    // then fused LSTM pointwise. Two halves (one per m-wave) reusing the tile LDS.
    float* zbuf = (float*)lds;
    const int f = tid & 63;
    const float bi = bias[f], bfv = bias[64 + f], bcv = bias[128 + f], bov = bias[192 + f];

#pragma unroll 1
    for (int half = 0; half < 2; ++half) {
        if (wm == half) {
#pragma unroll
            for (int mf = 0; mf < 4; ++mf)
#pragma unroll
                for (int nf = 0; nf < 4; ++nf)
#pragma unroll
                    for (int j = 0; j < 4; ++j)
                        zbuf[(mf * 16 + lg * 4 + j) * 256 + wn * 64 + nf * 16 + lm] =
                            acc[mf][nf][j];
        }
        __syncthreads();
        const int gy = y0 + half;
#pragma unroll 1
        for (int k2 = 0; k2 < 8; ++k2) {
            const int x = (tid >> 6) + k2 * 8;          // 0..63
            const float* zz = zbuf + x * 256;
            float zi = zz[f]       + bi;
            float zfv = zz[64 + f]  + bfv;
            float zc = zz[128 + f] + bcv;
            float zo = zz[192 + f] + bov;
            size_t goff = (((size_t)bb * NH + gy) * NW + x) * NF + f;
            float cp = cprev[goff];
            float ig = hsig(zi), fg = hsig(zfv), og = hsig(zo);
            float cn = fg * cp + ig * tanhf(zc);
            cnew[goff] = cn;
            float hn = og * tanhf(cn);
            hout[(size_t)bb * OUT_BSTRIDE + (((size_t)gy * NW + x) * NF + f)] = hn;
            size_t p2 = (((size_t)bb * NH + gy) * NW + x) * 128 + f;
            f16 hi = (f16)hn;
            h2out[p2]      = hi;
            h2out[p2 + 64] = (f16)(hn - (float)hi);
        }
        __syncthreads();
    }
}

extern "C" void kernel_launch(void* const* d_in, const int* in_sizes, int n_in,
                              void* d_out, int out_size, void* d_ws, size_t ws_size,
                              hipStream_t stream) {
    const float* h0    = (const float*)d_in[1];
    const float* c0    = (const float*)d_in[2];
    const float* kern  = (const float*)d_in[3];
    const float* rkern = (const float*)d_in[4];
    const float* bias  = (const float*)d_in[5];
    float* out = (float*)d_out;

    // workspace carve-up
    f16* wf2 = (f16*)d_ws;                                   // 16*9*256*128 f16 = 9.4 MB
    f16* h2a = wf2 + (size_t)NT * 9 * NG * 128;              // 16*64*64*128 f16 = 16.8 MB
    f16* h2b = h2a + (size_t)NB * NH * NW * 128;             // 16.8 MB
    float* cbuf = (float*)(h2b + (size_t)NB * NH * NW * 128); // 16.8 MB

    fuse_split_w<<<(NT * 9 * NG * NF + 255) / 256, 256, 0, stream>>>(kern, rkern, wf2);
    split_h<<<((int)(NB * HWF) + 255) / 256, 256, 0, stream>>>(h0, h2a);

    dim3 grid(NH / 2, NB);
    for (int t = 0; t < NT; ++t) {
        const f16* hin = (t & 1) ? h2b : h2a;
        f16* hnx       = (t & 1) ? h2a : h2b;
        convlstm_mfma_step<<<grid, 512, 0, stream>>>(
            hin, hnx,
            (t == 0) ? c0 : cbuf, cbuf,
            out + (size_t)t * HWF,
            wf2 + (size_t)t * 9 * NG * 128,
            bias + t * NG);
    }
}

// Round 3
// 1477.107 us; speedup vs baseline: 2.6793x; 1.0156x over previous
//
#include <hip/hip_runtime.h>
#include <math.h>

typedef _Float16 f16;
typedef _Float16 f16x8 __attribute__((ext_vector_type(8)));
typedef float f32x4 __attribute__((ext_vector_type(4)));

#define NB 16      // batch
#define NT 16      // time steps
#define NH 64
#define NW 64
#define NF 64      // features
#define NG 256     // 4*F
#define HWF ((size_t)NH * NW * NF)          // 262144
#define OUT_BSTRIDE ((size_t)NT * HWF)      // d_out batch stride
#define RS 16896                            // LDS row stride = 66 * 256 B (x-padded)

#define MFMA(a, b, c) __builtin_amdgcn_mfma_f32_16x16x32_f16((a), (b), (c), 0, 0, 0)

__device__ __forceinline__ void gload_lds16(const void* g, void* l) {
    __builtin_amdgcn_global_load_lds(
        (const __attribute__((address_space(1))) unsigned int*)(g),
        (__attribute__((address_space(3))) unsigned int*)(l), 16, 0, 0);
}

__device__ __forceinline__ float hsig(float x) {
    return fminf(fmaxf(0.2f * x + 0.5f, 0.0f), 1.0f);
}

// ---- prologue 1: fuse W+U, split fp16 hi/lo, layout [t*9+tap][cout][hi(64)|lo(64)]
__global__ void fuse_split_w(const float* __restrict__ k, const float* __restrict__ rk,
                             f16* __restrict__ wf2) {
    int idx = blockIdx.x * 256 + threadIdx.x;      // over 16*9*256*64
    if (idx >= NT * 9 * NG * NF) return;
    int cin  = idx & 63;
    int cout = (idx >> 6) & 255;
    int tt   = idx >> 14;                          // t*9 + tap
    size_t src = ((size_t)tt * NF + cin) * NG + cout;
    float w = k[src] + rk[src];
    f16 hi = (f16)w;
    size_t dst = ((size_t)tt * NG + cout) * 128 + cin;
    wf2[dst]      = hi;
    wf2[dst + 64] = (f16)(w - (float)hi);
}

// ---- prologue 2: split h0 to fp16 hi/lo, layout [b][y][x][hi(64)|lo(64)]
__global__ void split_h(const float* __restrict__ h0, f16* __restrict__ h2) {
    int idx = blockIdx.x * 256 + threadIdx.x;      // over 16*64*64*64
    if (idx >= (int)(NB * HWF)) return;
    int f = idx & 63;
    size_t p = (size_t)(idx >> 6);
    float v = h0[idx];
    f16 hi = (f16)v;
    h2[p * 128 + f]      = hi;
    h2[p * 128 + 64 + f] = (f16)(v - (float)hi);
}

// ---- one ConvLSTM step via split-fp16 MFMA implicit conv.
// 512 threads = 8 waves (2 m x 4 n). Block tile: 128 positions (2 rows) x 256 couts.
// LDS h tile: [4 rows][sx 0..65][hi128|lo128], x-padded (sx=0,65 are zero) so the
// K-loop has NO boundary clamps; XOR swizzle slot = k16 ^ (sx&7).
__global__ void __launch_bounds__(512, 2)
convlstm_mfma_step(const f16* __restrict__ h2in,
                   f16* __restrict__ h2out,
                   const float* __restrict__ cprev,
                   float* __restrict__ cnew,
                   float* __restrict__ hout,        // d_out + t*HWF
                   const f16* __restrict__ wt,      // [9][256][128] for this t
                   const float* __restrict__ bias)  // [256] for this t
{
    __shared__ __align__(16) unsigned char lds[4 * RS];   // 67584 B

    const int tid  = threadIdx.x;
    const int w    = tid >> 6;
    const int lane = tid & 63;
    const int bb   = blockIdx.y;
    const int y0   = blockIdx.x * 2;

    // zero the pad columns sx=0 and sx=65 (4 rows x 2 x 256B)
    if (tid < 128) {
        int row = tid >> 5, side = (tid >> 4) & 1, j = tid & 15;
        *(f16x8*)&lds[row * RS + side * (65 * 256) + j * 16] = (f16x8)(_Float16)0.0f;
    }

    // stage rows y0-1 .. y0+2 with pre-swizzled global source (rule 21)
    {
        const int r    = w >> 1;               // tile row 0..3
        const int gy   = y0 - 1 + r;
        const int half = w & 1;
        const unsigned dbase = r * RS + 256 + half * 8192;   // wave-uniform
        if (gy >= 0 && gy < NH) {
            const unsigned char* gsrc = (const unsigned char*)h2in +
                ((((size_t)bb * NH + gy) * NW) << 8);        // 256 B per (y,x)
            const int j = lane & 15;
#pragma unroll
            for (int i = 0; i < 8; ++i) {
                const int xrel = half * 32 + i * 4 + (lane >> 4);
                const unsigned src = ((unsigned)xrel << 8) +
                                     ((unsigned)(j ^ ((xrel + 1) & 7)) << 4);
                gload_lds16(gsrc + src, (void*)&lds[dbase + i * 1024]);
            }
        } else {
            const f16x8 zf = (f16x8)(_Float16)0.0f;
#pragma unroll
            for (int i = 0; i < 8; ++i)
                *(f16x8*)&lds[dbase + i * 1024 + lane * 16] = zf;
        }
    }
    __syncthreads();

    // ---------- K loop: 9 taps x 2 cin-halves, fully unrolled, 3-term split MFMA
    const int wm = w >> 2;     // 0..1 : image row within pair
    const int wn = w & 3;      // 0..3 : gate block of 64
    const int lm = lane & 15;
    const int lg = lane >> 4;

    f32x4 acc[4][4];
#pragma unroll
    for (int mf = 0; mf < 4; ++mf)
#pragma unroll
        for (int nf = 0; nf < 4; ++nf) acc[mf][nf] = (f32x4)0.0f;

    // per-lane swizzled A base offsets for dx in {-1,0,1} x kk in {0,1}
    unsigned av[3][2];
#pragma unroll
    for (int d = 0; d < 3; ++d)
#pragma unroll
        for (int kk = 0; kk < 2; ++kk) {
            const int sxl = lm + d;            // 0..17
            av[d][kk] = (unsigned)(sxl * 256 +
                        ((kk * 64 + lg * 16) ^ ((sxl & 7) << 4)));
        }

    // B base in f16x8 units: ((tap*256 + wn*64 + nf*16 + lm)*16 + kk*4 + lg)
    const f16x8* wbn = (const f16x8*)wt + ((size_t)(wn * 64 + lm) * 16 + lg);

    f16x8 bh[2][4], bl[2][4];
#define LOADB(P, IT)                                                    \
    {                                                                   \
        const int tap_ = (IT) >> 1, kk_ = (IT) & 1;                     \
        _Pragma("unroll")                                               \
        for (int nf = 0; nf < 4; ++nf) {                                \
            const f16x8* p = wbn + (tap_ * 4096 + nf * 256 + kk_ * 4);  \
            bh[P][nf] = p[0];                                           \
            bl[P][nf] = p[8];                                           \
        }                                                               \
    }

    LOADB(0, 0);
#pragma unroll
    for (int it = 0; it < 18; ++it) {
        if (it + 1 < 18) LOADB((it + 1) & 1, it + 1);
        const int tap = it >> 1, kk = it & 1;
        const int ty  = tap / 3;               // compile-time after unroll
        const int d   = tap - ty * 3;
        const unsigned abase = (unsigned)((wm + ty) * RS) + av[d][kk];
#pragma unroll
        for (int mf = 0; mf < 4; ++mf) {
            const f16x8 ah = *(const f16x8*)&lds[abase + mf * 4096];
            const f16x8 al = *(const f16x8*)&lds[abase + mf * 4096 + 128];
#pragma unroll
            for (int nf = 0; nf < 4; ++nf) {
                acc[mf][nf] = MFMA(ah, bh[it & 1][nf], acc[mf][nf]);
                acc[mf][nf] = MFMA(al, bh[it & 1][nf], acc[mf][nf]);
                acc[mf][nf] = MFMA(ah, bl[it & 1][nf], acc[mf][nf]);
            }
        }
    }
#undef LOADB

    __syncthreads();

    // ---------- epilogue: z-exchange through LDS, fused LSTM pointwise
    float* zbuf = (float*)lds;
    const int f = tid & 63;
    const float bi = bias[f], bfv = bias[64 + f], bcv = bias[128 + f], bov = bias[192 + f];

#pragma unroll 1
    for (int half = 0; half < 2; ++half) {
        if (wm == half) {
#pragma unroll
            for (int mf = 0; mf < 4; ++mf)
#pragma unroll
                for (int nf = 0; nf < 4; ++nf)
#pragma unroll
                    for (int j = 0; j < 4; ++j)
                        zbuf[(mf * 16 + lg * 4 + j) * 256 + wn * 64 + nf * 16 + lm] =
                            acc[mf][nf][j];
        }
        __syncthreads();
        const int gy = y0 + half;
#pragma unroll 1
        for (int k2 = 0; k2 < 8; ++k2) {
            const int x = (tid >> 6) + k2 * 8;          // 0..63 (wave-uniform)
            const float* zz = zbuf + x * 256;
            float zi  = zz[f]       + bi;
            float zfv = zz[64 + f]  + bfv;
            float zc  = zz[128 + f] + bcv;
            float zo  = zz[192 + f] + bov;
            size_t goff = (((size_t)bb * NH + gy) * NW + x) * NF + f;
            float cp = cprev[goff];
            float ig = hsig(zi), fg = hsig(zfv), og = hsig(zo);
            float cn = fg * cp + ig * tanhf(zc);
            cnew[goff] = cn;
            float hn = og * tanhf(cn);
            hout[(size_t)bb * OUT_BSTRIDE + (((size_t)gy * NW + x) * NF + f)] = hn;
            size_t p2 = (((size_t)bb * NH + gy) * NW + x) * 128 + f;
            f16 hi = (f16)hn;
            h2out[p2]      = hi;
            h2out[p2 + 64] = (f16)(hn - (float)hi);
        }
        __syncthreads();
    }
}

extern "C" void kernel_launch(void* const* d_in, const int* in_sizes, int n_in,
                              void* d_out, int out_size, void* d_ws, size_t ws_size,
                              hipStream_t stream) {
    const float* h0    = (const float*)d_in[1];
    const float* c0    = (const float*)d_in[2];
    const float* kern  = (const float*)d_in[3];
    const float* rkern = (const float*)d_in[4];
    const float* bias  = (const float*)d_in[5];
    float* out = (float*)d_out;

    f16* wf2 = (f16*)d_ws;                                    // 9.4 MB
    f16* h2a = wf2 + (size_t)NT * 9 * NG * 128;               // 16.8 MB
    f16* h2b = h2a + (size_t)NB * NH * NW * 128;              // 16.8 MB
    float* cbuf = (float*)(h2b + (size_t)NB * NH * NW * 128); // 16.8 MB

    fuse_split_w<<<(NT * 9 * NG * NF + 255) / 256, 256, 0, stream>>>(kern, rkern, wf2);
    split_h<<<((int)(NB * HWF) + 255) / 256, 256, 0, stream>>>(h0, h2a);

    dim3 grid(NH / 2, NB);
    for (int t = 0; t < NT; ++t) {
        const f16* hin = (t & 1) ? h2b : h2a;
        f16* hnx       = (t & 1) ? h2a : h2b;
        convlstm_mfma_step<<<grid, 512, 0, stream>>>(
            hin, hnx,
            (t == 0) ? c0 : cbuf, cbuf,
            out + (size_t)t * HWF,
            wf2 + (size_t)t * 9 * NG * 128,
            bias + t * NG);
    }
}

// Round 4
// 1395.079 us; speedup vs baseline: 2.8368x; 1.0588x over previous
//
#include <hip/hip_runtime.h>
#include <math.h>

typedef _Float16 f16;
typedef _Float16 f16x8 __attribute__((ext_vector_type(8)));
typedef float f32x4 __attribute__((ext_vector_type(4)));

#define NB 16      // batch
#define NT 16      // time steps
#define NH 64
#define NW 64
#define NF 64      // features
#define NG 256     // 4*F
#define HWF ((size_t)NH * NW * NF)          // 262144
#define OUT_BSTRIDE ((size_t)NT * HWF)      // d_out batch stride
#define RS 16896                            // LDS row stride = 66 * 256 B (x-padded)

#define MFMA(a, b, c) __builtin_amdgcn_mfma_f32_16x16x32_f16((a), (b), (c), 0, 0, 0)

__device__ __forceinline__ void gload_lds16(const void* g, void* l) {
    __builtin_amdgcn_global_load_lds(
        (const __attribute__((address_space(1))) unsigned int*)(g),
        (__attribute__((address_space(3))) unsigned int*)(l), 16, 0, 0);
}

__device__ __forceinline__ float hsig(float x) {
    return fminf(fmaxf(0.2f * x + 0.5f, 0.0f), 1.0f);
}

// ---- prologue 1: fuse W+U, split fp16 hi/lo, layout [t*9+tap][cout][hi(64)|lo(64)]
__global__ void fuse_split_w(const float* __restrict__ k, const float* __restrict__ rk,
                             f16* __restrict__ wf2) {
    int idx = blockIdx.x * 256 + threadIdx.x;      // over 16*9*256*64
    if (idx >= NT * 9 * NG * NF) return;
    int cin  = idx & 63;
    int cout = (idx >> 6) & 255;
    int tt   = idx >> 14;                          // t*9 + tap
    size_t src = ((size_t)tt * NF + cin) * NG + cout;
    float w = k[src] + rk[src];
    f16 hi = (f16)w;
    size_t dst = ((size_t)tt * NG + cout) * 128 + cin;
    wf2[dst]      = hi;
    wf2[dst + 64] = (f16)(w - (float)hi);
}

// ---- prologue 2: split h0 to fp16 hi/lo, layout [b][y][x][hi(64)|lo(64)]
__global__ void split_h(const float* __restrict__ h0, f16* __restrict__ h2) {
    int idx = blockIdx.x * 256 + threadIdx.x;      // over 16*64*64*64
    if (idx >= (int)(NB * HWF)) return;
    int f = idx & 63;
    size_t p = (size_t)(idx >> 6);
    float v = h0[idx];
    f16 hi = (f16)v;
    h2[p * 128 + f]      = hi;
    h2[p * 128 + 64 + f] = (f16)(v - (float)hi);
}

// ---- one ConvLSTM step via split-fp16 MFMA implicit conv.
// 512 threads = 8 waves (2 m x 4 n). Block tile: 128 positions (2 rows) x 256 couts.
// VGPR capped at 128 (launch_bounds min 4 waves/EU) + LDS 67.6KB -> 2 blocks/CU,
// so stage/epilogue/barrier drains of one block hide under the other's K-loop.
// B is single-buffered (32 VGPR); 4 waves/SIMD hide the per-iter L2 latency.
__global__ void __launch_bounds__(512, 4)
convlstm_mfma_step(const f16* __restrict__ h2in,
                   f16* __restrict__ h2out,
                   const float* __restrict__ cprev,
                   float* __restrict__ cnew,
                   float* __restrict__ hout,        // d_out + t*HWF
                   const f16* __restrict__ wt,      // [9][256][128] for this t
                   const float* __restrict__ bias)  // [256] for this t
{
    __shared__ __align__(16) unsigned char lds[4 * RS];   // 67584 B

    const int tid  = threadIdx.x;
    const int w    = tid >> 6;
    const int lane = tid & 63;
    const int bb   = blockIdx.y;
    const int y0   = blockIdx.x * 2;

    // zero the pad columns sx=0 and sx=65 (4 rows x 2 x 256B)
    if (tid < 128) {
        int row = tid >> 5, side = (tid >> 4) & 1, j = tid & 15;
        *(f16x8*)&lds[row * RS + side * (65 * 256) + j * 16] = (f16x8)(_Float16)0.0f;
    }

    // stage rows y0-1 .. y0+2 with pre-swizzled global source (rule 21)
    {
        const int r    = w >> 1;               // tile row 0..3
        const int gy   = y0 - 1 + r;
        const int half = w & 1;
        const unsigned dbase = r * RS + 256 + half * 8192;   // wave-uniform
        if (gy >= 0 && gy < NH) {
            const unsigned char* gsrc = (const unsigned char*)h2in +
                ((((size_t)bb * NH + gy) * NW) << 8);        // 256 B per (y,x)
            const int j = lane & 15;
#pragma unroll
            for (int i = 0; i < 8; ++i) {
                const int xrel = half * 32 + i * 4 + (lane >> 4);
                const unsigned src = ((unsigned)xrel << 8) +
                                     ((unsigned)(j ^ ((xrel + 1) & 7)) << 4);
                gload_lds16(gsrc + src, (void*)&lds[dbase + i * 1024]);
            }
        } else {
            const f16x8 zf = (f16x8)(_Float16)0.0f;
#pragma unroll
            for (int i = 0; i < 8; ++i)
                *(f16x8*)&lds[dbase + i * 1024 + lane * 16] = zf;
        }
    }
    __syncthreads();

    // ---------- K loop: 9 taps x 2 cin-halves, fully unrolled, 3-term split MFMA
    const int wm = w >> 2;     // 0..1 : image row within pair
    const int wn = w & 3;      // 0..3 : gate block of 64
    const int lm = lane & 15;
    const int lg = lane >> 4;

    f32x4 acc[4][4];
#pragma unroll
    for (int mf = 0; mf < 4; ++mf)
#pragma unroll
        for (int nf = 0; nf < 4; ++nf) acc[mf][nf] = (f32x4)0.0f;

    // per-lane swizzled A base offsets for dx in {-1,0,1} x kk in {0,1}
    unsigned av[3][2];
#pragma unroll
    for (int d = 0; d < 3; ++d)
#pragma unroll
        for (int kk = 0; kk < 2; ++kk) {
            const int sxl = lm + d;            // 0..17
            av[d][kk] = (unsigned)(sxl * 256 +
                        ((kk * 64 + lg * 16) ^ ((sxl & 7) << 4)));
        }

    // B base in f16x8 units: ((tap*256 + wn*64 + nf*16 + lm)*16 + kk*4 + lg)
    const f16x8* wbn = (const f16x8*)wt + ((size_t)(wn * 64 + lm) * 16 + lg);

    f16x8 bh[4], bl[4];        // single-buffered B (32 VGPR)

#pragma unroll
    for (int it = 0; it < 18; ++it) {
        const int tap = it >> 1, kk = it & 1;
        {
#pragma unroll
            for (int nf = 0; nf < 4; ++nf) {
                const f16x8* p = wbn + (tap * 4096 + nf * 256 + kk * 4);
                bh[nf] = p[0];
                bl[nf] = p[8];
            }
        }
        const int ty = tap / 3;                // compile-time after unroll
        const int d  = tap - ty * 3;
        const unsigned abase = (unsigned)((wm + ty) * RS) + av[d][kk];
        __builtin_amdgcn_s_setprio(1);
#pragma unroll
        for (int mf = 0; mf < 4; ++mf) {
            const f16x8 ah = *(const f16x8*)&lds[abase + mf * 4096];
            const f16x8 al = *(const f16x8*)&lds[abase + mf * 4096 + 128];
#pragma unroll
            for (int nf = 0; nf < 4; ++nf) {
                acc[mf][nf] = MFMA(ah, bh[nf], acc[mf][nf]);
                acc[mf][nf] = MFMA(al, bh[nf], acc[mf][nf]);
                acc[mf][nf] = MFMA(ah, bl[nf], acc[mf][nf]);
            }
        }
        __builtin_amdgcn_s_setprio(0);
    }

    __syncthreads();

    // ---------- epilogue: z-exchange through LDS, fused LSTM pointwise
    float* zbuf = (float*)lds;
    const int f = tid & 63;
    const float bi = bias[f], bfv = bias[64 + f], bcv = bias[128 + f], bov = bias[192 + f];

#pragma unroll 1
    for (int half = 0; half < 2; ++half) {
        if (wm == half) {
#pragma unroll
            for (int mf = 0; mf < 4; ++mf)
#pragma unroll
                for (int nf = 0; nf < 4; ++nf)
#pragma unroll
                    for (int j = 0; j < 4; ++j)
                        zbuf[(mf * 16 + lg * 4 + j) * 256 + wn * 64 + nf * 16 + lm] =
                            acc[mf][nf][j];
        }
        __syncthreads();
        const int gy = y0 + half;
#pragma unroll 1
        for (int k2 = 0; k2 < 8; ++k2) {
            const int x = (tid >> 6) + k2 * 8;          // 0..63 (wave-uniform)
            const float* zz = zbuf + x * 256;
            float zi  = zz[f]       + bi;
            float zfv = zz[64 + f]  + bfv;
            float zc  = zz[128 + f] + bcv;
            float zo  = zz[192 + f] + bov;
            size_t goff = (((size_t)bb * NH + gy) * NW + x) * NF + f;
            float cp = cprev[goff];
            float ig = hsig(zi), fg = hsig(zfv), og = hsig(zo);
            float cn = fg * cp + ig * tanhf(zc);
            cnew[goff] = cn;
            float hn = og * tanhf(cn);
            hout[(size_t)bb * OUT_BSTRIDE + (((size_t)gy * NW + x) * NF + f)] = hn;
            size_t p2 = (((size_t)bb * NH + gy) * NW + x) * 128 + f;
            f16 hi = (f16)hn;
            h2out[p2]      = hi;
            h2out[p2 + 64] = (f16)(hn - (float)hi);
        }
        __syncthreads();
    }
}

extern "C" void kernel_launch(void* const* d_in, const int* in_sizes, int n_in,
                              void* d_out, int out_size, void* d_ws, size_t ws_size,
                              hipStream_t stream) {
    const float* h0    = (const float*)d_in[1];
    const float* c0    = (const float*)d_in[2];
    const float* kern  = (const float*)d_in[3];
    const float* rkern = (const float*)d_in[4];
    const float* bias  = (const float*)d_in[5];
    float* out = (float*)d_out;

    f16* wf2 = (f16*)d_ws;                                    // 9.4 MB
    f16* h2a = wf2 + (size_t)NT * 9 * NG * 128;               // 16.8 MB
    f16* h2b = h2a + (size_t)NB * NH * NW * 128;              // 16.8 MB
    float* cbuf = (float*)(h2b + (size_t)NB * NH * NW * 128); // 16.8 MB

    fuse_split_w<<<(NT * 9 * NG * NF + 255) / 256, 256, 0, stream>>>(kern, rkern, wf2);
    split_h<<<((int)(NB * HWF) + 255) / 256, 256, 0, stream>>>(h0, h2a);

    dim3 grid(NH / 2, NB);
    for (int t = 0; t < NT; ++t) {
        const f16* hin = (t & 1) ? h2b : h2a;
        f16* hnx       = (t & 1) ? h2a : h2b;
        convlstm_mfma_step<<<grid, 512, 0, stream>>>(
            hin, hnx,
            (t == 0) ? c0 : cbuf, cbuf,
            out + (size_t)t * HWF,
            wf2 + (size_t)t * 9 * NG * 128,
            bias + t * NG);
    }
}